// Round 5
// baseline (711.514 us; speedup 1.0000x reference)
//
#include <hip/hip_runtime.h>
#include <stdint.h>

// Problem constants (fixed by reference)
#define BATCH 2
#define TLEN  2048
#define DEMB  2048
#define NHQ   16
#define NHKV  4
#define GRP   4
#define DKV   128
#define ATTN_OUT_ELEMS (BATCH*TLEN*DEMB) // 8388608
// d_out layout: [attn_output (8388608 f32) | kv_cache (B,T,4,256) f32 (4194304)]

typedef __bf16 bf16_t;
typedef __attribute__((ext_vector_type(4))) __bf16 bf16x4;
typedef __attribute__((ext_vector_type(8))) __bf16 bf16x8;
typedef __attribute__((ext_vector_type(4))) float f32x4;

__device__ __forceinline__ f32x4 mfma16(bf16x8 a, bf16x8 b, f32x4 c) {
  return __builtin_amdgcn_mfma_f32_16x16x32_bf16(a, b, c, 0, 0, 0);
}

typedef __attribute__((address_space(1))) const unsigned int as1_uint;
typedef __attribute__((address_space(3))) unsigned int as3_uint;
__device__ __forceinline__ void gload_lds16(const void* g, void* l) {
  // 16B per lane, LDS dest = l + lane*16 (wave-uniform base)
  __builtin_amdgcn_global_load_lds((as1_uint*)g, (as3_uint*)l, 16, 0, 0);
}

// ---------------------------------------------------------------------------
// threefry2x32-20, key=(0,1) (jax.random.key(1)), partitionable mode:
// per-element u64 counter (hi=0, lo=ctr), output = x0 ^ x1. Verified R1/R4.
// keep = uniform<0.9  <=>  bits < 0xE6666600 (bit-exact, verified R4).
// rotl via v_alignbit_b32 (1 instr guaranteed).
// ---------------------------------------------------------------------------
__device__ __forceinline__ uint32_t rotl(uint32_t x, int r) {
  return __builtin_amdgcn_alignbit(x, x, 32 - r);
}
__device__ __forceinline__ void tf_round(uint32_t& x0, uint32_t& x1, int r) {
  x0 += x1;
  x1 = rotl(x1, r);
  x1 ^= x0;
}
__device__ __forceinline__ uint32_t threefry_bits(uint32_t ctr) {
  const uint32_t ks1 = 1u, ks2 = 0x1BD11BDBu;
  uint32_t x0 = 0u, x1 = ctr + ks1;
  tf_round(x0,x1,13); tf_round(x0,x1,15); tf_round(x0,x1,26); tf_round(x0,x1,6);
  x0 += ks1; x1 += ks2 + 1u;
  tf_round(x0,x1,17); tf_round(x0,x1,29); tf_round(x0,x1,16); tf_round(x0,x1,24);
  x0 += ks2; x1 += 0u + 2u;
  tf_round(x0,x1,13); tf_round(x0,x1,15); tf_round(x0,x1,26); tf_round(x0,x1,6);
  x0 += 0u;  x1 += ks1 + 3u;
  tf_round(x0,x1,17); tf_round(x0,x1,29); tf_round(x0,x1,16); tf_round(x0,x1,24);
  x0 += ks1; x1 += ks2 + 4u;
  tf_round(x0,x1,13); tf_round(x0,x1,15); tf_round(x0,x1,26); tf_round(x0,x1,6);
  x0 += ks2; x1 += 0u + 5u;
  return x0 ^ x1;
}

// ---------------------------------------------------------------------------
// Dropout mask precompute: packed u64 words, layout [bgh=32][ti=2048][32 words]
// word w bit i = keep(element tj = w*64 + i). Only causal words (w <= ti/64)
// are generated. Pure-ALU kernel at ~max occupancy; row pairing (ti, 2047-ti)
// makes every wave's cost uniform.
// ---------------------------------------------------------------------------
__global__ __launch_bounds__(256, 8) void mask_gen(uint64_t* __restrict__ mask) {
  const int wid = blockIdx.x * 4 + (threadIdx.x >> 6);   // 0..8191
  const int lane = threadIdx.x & 63;
#pragma unroll
  for (int j = 0; j < 4; ++j) {
    const int base = j * 16384;
#pragma unroll
    for (int s = 0; s < 2; ++s) {
      const int flat = s == 0 ? (base + wid) : (base + 16383 - wid); // bgh*2048+ti
      const int ti = flat & (TLEN - 1);
      const int nW = (ti >> 6) + 1;
      const uint32_t cbase = ((uint32_t)flat << 11) + (uint32_t)lane;
      uint64_t w_local = 0;
      for (int wd = 0; wd < nW; ++wd) {
        uint32_t bits = threefry_bits(cbase + ((uint32_t)wd << 6));
        uint64_t blt = __ballot(bits < 0xE6666600u);
        if (lane == wd) w_local = blt;
      }
      if (lane < nW) mask[(size_t)flat * 32 + lane] = w_local;
    }
  }
}

// ---------------------------------------------------------------------------
// RoPE cos/sin tables [ti=2048][d=64] (double-precision generation).
// ---------------------------------------------------------------------------
__global__ __launch_bounds__(256) void rope_tab(float* __restrict__ ct,
                                                float* __restrict__ st) {
  int i = blockIdx.x * 256 + threadIdx.x;     // 131072 total
  int ti = i >> 6, d = i & 63;
  double theta = exp((double)(-2 * d) * (9.210340371976184 / 128.0)); // ln(1e4)/128
  float tick = (float)ti * (float)theta;
  ct[i] = (float)cos((double)tick);
  st[i] = (float)sin((double)tick);
}

// ---------------------------------------------------------------------------
// fp32 -> bf16 convert (X)
// ---------------------------------------------------------------------------
__global__ __launch_bounds__(256) void cvt_bf16(const float* __restrict__ src,
                                                bf16_t* __restrict__ dst, int n4) {
  int i = (blockIdx.x * 256 + threadIdx.x);
  if (i < n4) {
    float4 v = *(const float4*)(src + (size_t)i * 4);
    bf16x4 o = {(bf16_t)v.x, (bf16_t)v.y, (bf16_t)v.z, (bf16_t)v.w};
    *(bf16x4*)(dst + (size_t)i * 4) = o;
  }
}

// ---------------------------------------------------------------------------
// Weight transpose+convert: src f32 [K][N] -> dst bf16 [N][Kd]; one dispatch
// covers wq/wk/wv/wo.
// ---------------------------------------------------------------------------
__device__ __forceinline__ void wtrans_body(const float* __restrict__ src,
                                            bf16_t* __restrict__ dst,
                                            int N, int Kd, int k0, int n0) {
  __shared__ float t[64][65];
  const int tid = threadIdx.x;
  const int r = tid >> 4, c4 = tid & 15;
#pragma unroll
  for (int i = 0; i < 4; ++i) {
    float4 v = *(const float4*)(src + (size_t)(k0 + r + i * 16) * N + n0 + c4 * 4);
    t[r + i * 16][c4 * 4 + 0] = v.x; t[r + i * 16][c4 * 4 + 1] = v.y;
    t[r + i * 16][c4 * 4 + 2] = v.z; t[r + i * 16][c4 * 4 + 3] = v.w;
  }
  __syncthreads();
#pragma unroll
  for (int i = 0; i < 4; ++i) {
    int idx = tid + i * 256;
    int rn = idx >> 4, ck = idx & 15;
    bf16x4 o = {(bf16_t)t[ck * 4 + 0][rn], (bf16_t)t[ck * 4 + 1][rn],
                (bf16_t)t[ck * 4 + 2][rn], (bf16_t)t[ck * 4 + 3][rn]};
    *(bf16x4*)(dst + (size_t)(n0 + rn) * Kd + k0 + ck * 4) = o;
  }
}

__global__ __launch_bounds__(256) void wtrans_all(const float* __restrict__ wq,
                                                  const float* __restrict__ wk,
                                                  const float* __restrict__ wv,
                                                  const float* __restrict__ wo,
                                                  bf16_t* __restrict__ dqkv,
                                                  bf16_t* __restrict__ dwo) {
  const int by = blockIdx.y, k0 = blockIdx.x * 64;
  if (by < 32)      wtrans_body(wq, dqkv,                        2048, 2048, k0, by * 64);
  else if (by < 40) wtrans_body(wk, dqkv + (size_t)2048 * 2048,  512,  2048, k0, (by - 32) * 64);
  else if (by < 48) wtrans_body(wv, dqkv + (size_t)2560 * 2048,  512,  2048, k0, (by - 40) * 64);
  else              wtrans_body(wo, dwo,                         2048, 2048, k0, (by - 48) * 64);
}

// ---------------------------------------------------------------------------
// bf16 MFMA GEMM: C[M,N] = Ab[M,K] (row-major) @ Wt[N,K]^T
// 128x128 tile, BK=64, 4 waves, 64x64/wave; col-tile pairing keeps RoPE
// partners (d, d+64) in-wave for MODE 1. global_load_lds(16B) staging with
// XOR chunk swizzle. MODE 0: f32 C. MODE 1: QKV epilogue (RoPE via tables).
// ---------------------------------------------------------------------------
template<int MODE>
__global__ __launch_bounds__(256) void gemm_bf16(
    const bf16_t* __restrict__ Ab, const bf16_t* __restrict__ Wt,
    float* __restrict__ Cout, bf16_t* __restrict__ qbuf,
    bf16_t* __restrict__ Kbuf, float* __restrict__ kvout,
    const float* __restrict__ costab, const float* __restrict__ sintab,
    int M, int N, int K) {
  __shared__ bf16_t As[128 * 64];
  __shared__ bf16_t Bs[128 * 64];
  const int tid = threadIdx.x;
  const int w = tid >> 6, lane = tid & 63;
  const int lm = lane & 15, lg = lane >> 4;
  const int wy = w & 1, wx = w >> 1;
  const int mblk = blockIdx.x * 128, nblk = blockIdx.y * 128;

  const int srow = lane >> 3;                 // row within 8-row group
  const int schunk = (lane & 7) ^ srow;       // fetch swizzled chunk
  const bf16_t* Ag = Ab + (size_t)(mblk + w * 32 + srow) * K + schunk * 8;
  const bf16_t* Bg = Wt + (size_t)(nblk + w * 32 + srow) * K + schunk * 8;
  bf16_t* AsW = As + (w * 32) * 64;
  bf16_t* BsW = Bs + (w * 32) * 64;

  f32x4 acc[4][4];
#pragma unroll
  for (int i = 0; i < 4; ++i)
#pragma unroll
    for (int j = 0; j < 4; ++j) acc[i][j] = (f32x4)0.0f;

  const int tcol0 = wx * 2;

  for (int k0 = 0; k0 < K; k0 += 64) {
    __syncthreads();
#pragma unroll
    for (int inst = 0; inst < 4; ++inst) {
      gload_lds16(Ag + (size_t)(inst * 8) * K + k0, AsW + inst * 8 * 64);
      gload_lds16(Bg + (size_t)(inst * 8) * K + k0, BsW + inst * 8 * 64);
    }
    asm volatile("s_waitcnt vmcnt(0)" ::: "memory");
    __syncthreads();
#pragma unroll
    for (int ks = 0; ks < 2; ++ks) {
      const int chunk = ((ks * 4 + lg) ^ (lane & 7)) * 8;
      bf16x8 af[4], bfr[4];
#pragma unroll
      for (int i = 0; i < 4; ++i) {
        int mrow = wy * 64 + i * 16 + lm;
        af[i] = *(const bf16x8*)&As[mrow * 64 + chunk];
      }
#pragma unroll
      for (int j = 0; j < 4; ++j) {
        int tc = tcol0 + (j & 1) + (j >> 1) * 4;
        int nrow = tc * 16 + lm;
        bfr[j] = *(const bf16x8*)&Bs[nrow * 64 + chunk];
      }
#pragma unroll
      for (int i = 0; i < 4; ++i)
#pragma unroll
        for (int j = 0; j < 4; ++j) acc[i][j] = mfma16(af[i], bfr[j], acc[i][j]);
    }
  }

  if (MODE == 0) {
#pragma unroll
    for (int i = 0; i < 4; ++i)
#pragma unroll
      for (int j = 0; j < 4; ++j) {
        int tc = tcol0 + (j & 1) + (j >> 1) * 4;
        int col = nblk + tc * 16 + lm;
#pragma unroll
        for (int r = 0; r < 4; ++r) {
          int row = mblk + wy * 64 + i * 16 + lg * 4 + r;
          Cout[(size_t)row * N + col] = acc[i][j][r];
        }
      }
  } else {
    // QKV epilogue with fused RoPE via tables. d in [0,64), partner d+64.
    const float qscale = 0.08838834764831843f;   // 1/sqrt(128)
#pragma unroll
    for (int i = 0; i < 4; ++i) {
#pragma unroll
      for (int r = 0; r < 4; ++r) {
        int row = mblk + wy * 64 + i * 16 + lg * 4 + r;   // bt
        int ti = row & (TLEN - 1), b = row >> 11;
#pragma unroll
        for (int jp = 0; jp < 2; ++jp) {
          float lo = acc[i][jp][r], hi = acc[i][jp + 2][r];
          int d = wx * 32 + jp * 16 + lm;                 // [0,64)
          int nl = nblk + d;                              // low-half global col
          if (nblk < 2048) {                              // q
            int qh = nl >> 7;
            float cs = costab[ti * 64 + d], sn = sintab[ti * 64 + d];
            float o0 = (lo * cs - hi * sn) * qscale;
            float o1 = (hi * cs + lo * sn) * qscale;
            size_t qo = (((size_t)(b * 16 + qh)) * TLEN + ti) * 128 + d;
            qbuf[qo] = (bf16_t)o0; qbuf[qo + 64] = (bf16_t)o1;
          } else if (nblk < 2560) {                       // k
            int hh = (nl - 2048) >> 7;
            float cs = costab[ti * 64 + d], sn = sintab[ti * 64 + d];
            float o0 = lo * cs - hi * sn;
            float o1 = hi * cs + lo * sn;
            size_t ko = (((size_t)(b * 4 + hh)) * TLEN + ti) * 128 + d;
            Kbuf[ko] = (bf16_t)o0; Kbuf[ko + 64] = (bf16_t)o1;
            size_t kvo = (size_t)row * 1024 + hh * 256 + d;
            kvout[kvo] = o0; kvout[kvo + 64] = o1;
          } else {                                        // v
            int hh = (nl - 2560) >> 7;
            size_t kvo = (size_t)row * 1024 + hh * 256 + 128 + d;
            kvout[kvo] = lo; kvout[kvo + 64] = hi;
          }
        }
      }
    }
  }
}

// ---------------------------------------------------------------------------
// V transpose: kv f32 [b][ti][h][128v @ +128] -> Vtb bf16 [b][h][d=128][tj=2048]
// ---------------------------------------------------------------------------
__global__ __launch_bounds__(256) void vtrans(const float* __restrict__ kvout,
                                              bf16_t* __restrict__ Vtb) {
  __shared__ bf16_t t[128][72];
  const int bx = blockIdx.x;          // (b*4+h)*32 + tt
  const int tt = bx & 31, bh = bx >> 5;
  const int b = bh >> 2, h = bh & 3;
  const int ti0 = tt * 64;
  const float* src = kvout + ((size_t)b * TLEN + ti0) * 1024 + h * 256 + 128;
  for (int idx = threadIdx.x; idx < 64 * 32; idx += 256) {
    int ti = idx >> 5, c4 = idx & 31;
    float4 v = *(const float4*)(src + (size_t)ti * 1024 + c4 * 4);
    t[c4 * 4 + 0][ti] = (bf16_t)v.x; t[c4 * 4 + 1][ti] = (bf16_t)v.y;
    t[c4 * 4 + 2][ti] = (bf16_t)v.z; t[c4 * 4 + 3][ti] = (bf16_t)v.w;
  }
  __syncthreads();
  bf16_t* dst = Vtb + (size_t)bh * 128 * TLEN + ti0;
  for (int idx = threadIdx.x; idx < 128 * 16; idx += 256) {
    int d = idx >> 4, ck = idx & 15;
    bf16x4 o = {t[d][ck * 4 + 0], t[d][ck * 4 + 1], t[d][ck * 4 + 2], t[d][ck * 4 + 3]};
    *(bf16x4*)(dst + (size_t)d * TLEN + ck * 4) = o;
  }
}

// ---------------------------------------------------------------------------
// Flash attention, bf16 MFMA. Block = (b, qh, 64-row q-tile), 4 waves,
// wave w owns rows [qt*64 + w*16, +16). 64-col K-tiles, no barriers in
// K-loop (wave-private LDS strip for P C->A relayout). Dropout applied from
// precomputed packed mask (u64 per 64 cols). Online softmax via 16-lane
// shfl_xor. qt <-> 31-qt pairing across bx +- 512 balances causal work.
// ---------------------------------------------------------------------------
#define PSTR 68
__global__ __launch_bounds__(256, 4) void attn_flash(
    const bf16_t* __restrict__ qb, const bf16_t* __restrict__ Kb,
    const bf16_t* __restrict__ Vtb, const uint64_t* __restrict__ maskbuf,
    bf16_t* __restrict__ midb) {
  __shared__ bf16_t P_lds[64 * PSTR];
  const int tid = threadIdx.x;
  const int w = tid >> 6, lane = tid & 63;
  const int lm = lane & 15, lg = lane >> 4;

  const int bx = blockIdx.x;
  const int bhalf = bx >> 9, idx = bx & 511;
  const int bqh = idx & 31, t4 = idx >> 5;          // t4 in 0..15
  const int qt = bhalf ? (31 - t4) : t4;            // 0..31
  const int qh = bqh & 15, b = bqh >> 4;
  const int h = qh & 3, g = qh >> 2;

  const bf16_t* qbase = qb + (((size_t)(b * 16 + qh)) * TLEN + qt * 64 + w * 16) * 128;
  const bf16_t* kbase = Kb + ((size_t)(b * 4 + h)) * TLEN * 128;
  const bf16_t* vbase = Vtb + ((size_t)(b * 4 + h)) * 128 * TLEN;

  // Q A-frags (16 rows); q already scaled by 1/sqrt(128)
  bf16x8 qf[4];
#pragma unroll
  for (int kk = 0; kk < 4; ++kk)
    qf[kk] = *(const bf16x8*)(qbase + (size_t)lm * 128 + kk * 32 + lg * 8);

  float mrow[4], lrow[4];
  f32x4 Oacc[8];
#pragma unroll
  for (int r = 0; r < 4; ++r) { mrow[r] = -3.0e38f; lrow[r] = 0.f; }
#pragma unroll
  for (int c = 0; c < 8; ++c) Oacc[c] = (f32x4)0.0f;

  const int row0 = qt * 64 + w * 16;           // wave's first q row
  const int nkt = qt + 1;                      // K-tiles needed
  const float L2E = 1.4426950408889634f;
  const int hdr = (b * 4 + g) * 4 + h;         // bgh, matches mask layout
  bf16_t* Pw = P_lds + (w * 16) * PSTR;

  for (int kt = 0; kt < nkt; ++kt) {
    const int tj0 = kt * 64;
    // ---- S = Q K^T ----
    f32x4 S[4];
#pragma unroll
    for (int ct = 0; ct < 4; ++ct) S[ct] = (f32x4)0.0f;
#pragma unroll
    for (int ct = 0; ct < 4; ++ct) {
      bf16x8 kf[4];
#pragma unroll
      for (int kk = 0; kk < 4; ++kk)
        kf[kk] = *(const bf16x8*)(kbase + (size_t)(tj0 + ct * 16 + lm) * 128 + kk * 32 + lg * 8);
#pragma unroll
      for (int kk = 0; kk < 4; ++kk) S[ct] = mfma16(qf[kk], kf[kk], S[ct]);
    }

    // ---- causal mask (diagonal tile only) ----
    if (tj0 + 63 > row0) {
#pragma unroll
      for (int ct = 0; ct < 4; ++ct) {
        int tj = tj0 + ct * 16 + lm;
#pragma unroll
        for (int r = 0; r < 4; ++r) {
          int ti = row0 + lg * 4 + r;
          if (tj > ti) S[ct][r] = -1.0e30f;
        }
      }
    }

    // ---- online softmax ----
    float alpha[4];
    {
      float pm[4];
#pragma unroll
      for (int r = 0; r < 4; ++r)
        pm[r] = fmaxf(fmaxf(S[0][r], S[1][r]), fmaxf(S[2][r], S[3][r]));
#pragma unroll
      for (int off = 1; off < 16; off <<= 1)
#pragma unroll
        for (int r = 0; r < 4; ++r) pm[r] = fmaxf(pm[r], __shfl_xor(pm[r], off));
#pragma unroll
      for (int r = 0; r < 4; ++r) {
        float mn = fmaxf(mrow[r], pm[r]);
        alpha[r] = exp2f((mrow[r] - mn) * L2E);
        mrow[r] = mn;
      }
      float rs[4] = {0.f, 0.f, 0.f, 0.f};
#pragma unroll
      for (int ct = 0; ct < 4; ++ct)
#pragma unroll
        for (int r = 0; r < 4; ++r) {
          float p = exp2f((S[ct][r] - mrow[r]) * L2E);
          S[ct][r] = p;
          rs[r] += p;
        }
#pragma unroll
      for (int off = 1; off < 16; off <<= 1)
#pragma unroll
        for (int r = 0; r < 4; ++r) rs[r] += __shfl_xor(rs[r], off);
#pragma unroll
      for (int r = 0; r < 4; ++r) lrow[r] = lrow[r] * alpha[r] + rs[r];
    }

    // ---- dropout from precomputed mask + bf16 + LDS (C->A relayout) ----
#pragma unroll
    for (int r = 0; r < 4; ++r) {
      int ti = row0 + lg * 4 + r;
      uint64_t M = maskbuf[((size_t)(hdr * 2048 + ti)) * 32 + kt];
      uint32_t Ml = (uint32_t)M, Mh = (uint32_t)(M >> 32);
      int prow = (lg * 4 + r) * PSTR + lm;
      Pw[prow +  0] = (bf16_t)(((Ml >> lm) & 1u)        ? S[0][r] : 0.f);
      Pw[prow + 16] = (bf16_t)(((Ml >> (16 + lm)) & 1u) ? S[1][r] : 0.f);
      Pw[prow + 32] = (bf16_t)(((Mh >> lm) & 1u)        ? S[2][r] : 0.f);
      Pw[prow + 48] = (bf16_t)(((Mh >> (16 + lm)) & 1u) ? S[3][r] : 0.f);
    }
    asm volatile("s_waitcnt lgkmcnt(0)" ::: "memory");

    // ---- O = O*alpha + P V ----
#pragma unroll
    for (int c = 0; c < 8; ++c)
#pragma unroll
      for (int r = 0; r < 4; ++r) Oacc[c][r] *= alpha[r];

    bf16x8 aP[2];
#pragma unroll
    for (int kk = 0; kk < 2; ++kk)
      aP[kk] = *(const bf16x8*)&Pw[lm * PSTR + kk * 32 + lg * 8];
#pragma unroll
    for (int c = 0; c < 8; ++c) {
      bf16x8 vf[2];
#pragma unroll
      for (int kk = 0; kk < 2; ++kk)
        vf[kk] = *(const bf16x8*)(vbase + (size_t)(c * 16 + lm) * TLEN + tj0 + kk * 32 + lg * 8);
#pragma unroll
      for (int kk = 0; kk < 2; ++kk) Oacc[c] = mfma16(aP[kk], vf[kk], Oacc[c]);
    }
  }

  // ---- epilogue: normalize (1/l) * (1/0.9), write bf16 mid ----
  float invl[4];
#pragma unroll
  for (int r = 0; r < 4; ++r) invl[r] = (1.0f / 0.9f) / lrow[r];
#pragma unroll
  for (int c = 0; c < 8; ++c) {
    int d = c * 16 + lm;
#pragma unroll
    for (int r = 0; r < 4; ++r) {
      int bt = b * TLEN + row0 + lg * 4 + r;
      midb[(size_t)bt * DEMB + qh * 128 + d] = (bf16_t)(Oacc[c][r] * invl[r]);
    }
  }
}

// ---------------------------------------------------------------------------
extern "C" void kernel_launch(void* const* d_in, const int* in_sizes, int n_in,
                              void* d_out, int out_size, void* d_ws, size_t ws_size,
                              hipStream_t stream) {
  const float* x  = (const float*)d_in[0];
  const float* wq = (const float*)d_in[1];
  const float* wk = (const float*)d_in[2];
  const float* wv = (const float*)d_in[3];
  const float* wo = (const float*)d_in[4];
  float* out = (float*)d_out;
  float* kvc = out + ATTN_OUT_ELEMS;                    // [B,T,4,256] f32

  // workspace carve-up (~80.8 MB). maskbuf (16.78 MB) aliases Xb, which is
  // dead after gemm<1>; mask_gen runs after gemm<1>, before attn_flash.
  char* ws = (char*)d_ws;
  bf16_t* Xb     = (bf16_t*)ws;                          ws += (size_t)4096 * 2048 * 2;  // 16.8MB
  bf16_t* Wqkvt  = (bf16_t*)ws;                          ws += (size_t)3072 * 2048 * 2;  // 12.6MB
  bf16_t* Wot    = (bf16_t*)ws;                          ws += (size_t)2048 * 2048 * 2;  // 8.4MB
  bf16_t* qbuf   = (bf16_t*)ws;                          ws += (size_t)2 * 16 * 2048 * 128 * 2; // 16.8MB
  bf16_t* Kbuf   = (bf16_t*)ws;                          ws += (size_t)2 * 4 * 2048 * 128 * 2;  // 4.2MB
  bf16_t* Vtb    = (bf16_t*)ws;                          ws += (size_t)2 * 4 * 128 * 2048 * 2;  // 4.2MB
  bf16_t* midb   = (bf16_t*)ws;                          ws += (size_t)4096 * 2048 * 2;  // 16.8MB
  float*  costab = (float*)ws;                           ws += (size_t)2048 * 64 * 4;    // 0.5MB
  float*  sintab = (float*)ws;                           // 0.5MB
  uint64_t* maskbuf = (uint64_t*)Xb;                     // 32*2048*32*8 = 16.8MB alias

  dim3 blk(256);
  rope_tab<<<512, blk, 0, stream>>>(costab, sintab);
  cvt_bf16<<<8192, blk, 0, stream>>>(x, Xb, 8388608 / 4);
  wtrans_all<<<dim3(32, 80), blk, 0, stream>>>(wq, wk, wv, wo, Wqkvt, Wot);

  gemm_bf16<1><<<dim3(32, 24), blk, 0, stream>>>(Xb, Wqkvt, nullptr, qbuf, Kbuf, kvc,
                                                 costab, sintab, 4096, 3072, 2048);
  mask_gen<<<2048, blk, 0, stream>>>(maskbuf);           // Xb dead from here on
  vtrans<<<dim3(256), blk, 0, stream>>>(kvc, Vtb);
  attn_flash<<<dim3(1024), blk, 0, stream>>>(qbuf, Kbuf, Vtb, maskbuf, midb);
  gemm_bf16<0><<<dim3(32, 16), blk, 0, stream>>>(midb, Wot, out, nullptr, nullptr, nullptr,
                                                 nullptr, nullptr, 4096, 2048, 2048);
}

// Round 6
// 474.466 us; speedup vs baseline: 1.4996x; 1.4996x over previous
//
#include <hip/hip_runtime.h>
#include <stdint.h>

// Problem constants (fixed by reference)
#define BATCH 2
#define TLEN  2048
#define DEMB  2048
#define NHQ   16
#define NHKV  4
#define GRP   4
#define DKV   128
#define ATTN_OUT_ELEMS (BATCH*TLEN*DEMB) // 8388608
// d_out layout: [attn_output (8388608 f32) | kv_cache (B,T,4,256) f32 (4194304)]

typedef __bf16 bf16_t;
typedef __attribute__((ext_vector_type(4))) __bf16 bf16x4;
typedef __attribute__((ext_vector_type(8))) __bf16 bf16x8;
typedef __attribute__((ext_vector_type(4))) float f32x4;

__device__ __forceinline__ f32x4 mfma16(bf16x8 a, bf16x8 b, f32x4 c) {
  return __builtin_amdgcn_mfma_f32_16x16x32_bf16(a, b, c, 0, 0, 0);
}

typedef __attribute__((address_space(1))) const unsigned int as1_uint;
typedef __attribute__((address_space(3))) unsigned int as3_uint;
__device__ __forceinline__ void gload_lds16(const void* g, void* l) {
  // 16B per lane, LDS dest = l + lane*16 (wave-uniform base)
  __builtin_amdgcn_global_load_lds((as1_uint*)g, (as3_uint*)l, 16, 0, 0);
}

// ---------------------------------------------------------------------------
// threefry2x32-20, key=(0,1) (jax.random.key(1)), partitionable mode:
// per-element u64 counter (hi=0, lo=ctr), output = x0 ^ x1. Verified R1-R5.
// keep = uniform<0.9  <=>  bits < 0xE6666600 (bit-exact, verified R4/R5).
// ---------------------------------------------------------------------------
__device__ __forceinline__ uint32_t rotl(uint32_t x, int r) {
  return __builtin_amdgcn_alignbit(x, x, 32 - r);
}
__device__ __forceinline__ void tf_round(uint32_t& x0, uint32_t& x1, int r) {
  x0 += x1;
  x1 = rotl(x1, r);
  x1 ^= x0;
}
__device__ __forceinline__ uint32_t threefry_bits(uint32_t ctr) {
  const uint32_t ks1 = 1u, ks2 = 0x1BD11BDBu;
  uint32_t x0 = 0u, x1 = ctr + ks1;
  tf_round(x0,x1,13); tf_round(x0,x1,15); tf_round(x0,x1,26); tf_round(x0,x1,6);
  x0 += ks1; x1 += ks2 + 1u;
  tf_round(x0,x1,17); tf_round(x0,x1,29); tf_round(x0,x1,16); tf_round(x0,x1,24);
  x0 += ks2; x1 += 0u + 2u;
  tf_round(x0,x1,13); tf_round(x0,x1,15); tf_round(x0,x1,26); tf_round(x0,x1,6);
  x0 += 0u;  x1 += ks1 + 3u;
  tf_round(x0,x1,17); tf_round(x0,x1,29); tf_round(x0,x1,16); tf_round(x0,x1,24);
  x0 += ks1; x1 += ks2 + 4u;
  tf_round(x0,x1,13); tf_round(x0,x1,15); tf_round(x0,x1,26); tf_round(x0,x1,6);
  x0 += ks2; x1 += 0u + 5u;
  return x0 ^ x1;
}

// ---------------------------------------------------------------------------
// RoPE cos/sin tables [ti=2048][d=64] (double-precision generation).
// ---------------------------------------------------------------------------
__global__ __launch_bounds__(256) void rope_tab(float* __restrict__ ct,
                                                float* __restrict__ st) {
  int i = blockIdx.x * 256 + threadIdx.x;     // 131072 total
  int ti = i >> 6, d = i & 63;
  double theta = exp((double)(-2 * d) * (9.210340371976184 / 128.0)); // ln(1e4)/128
  float tick = (float)ti * (float)theta;
  ct[i] = (float)cos((double)tick);
  st[i] = (float)sin((double)tick);
}

// ---------------------------------------------------------------------------
// fp32 -> bf16 convert (X)
// ---------------------------------------------------------------------------
__global__ __launch_bounds__(256) void cvt_bf16(const float* __restrict__ src,
                                                bf16_t* __restrict__ dst, int n4) {
  int i = (blockIdx.x * 256 + threadIdx.x);
  if (i < n4) {
    float4 v = *(const float4*)(src + (size_t)i * 4);
    bf16x4 o = {(bf16_t)v.x, (bf16_t)v.y, (bf16_t)v.z, (bf16_t)v.w};
    *(bf16x4*)(dst + (size_t)i * 4) = o;
  }
}

// ---------------------------------------------------------------------------
// Weight transpose+convert: src f32 [K][N] -> dst bf16 [N][Kd]; one dispatch
// covers wq/wk/wv/wo.
// ---------------------------------------------------------------------------
__device__ __forceinline__ void wtrans_body(const float* __restrict__ src,
                                            bf16_t* __restrict__ dst,
                                            int N, int Kd, int k0, int n0) {
  __shared__ float t[64][65];
  const int tid = threadIdx.x;
  const int r = tid >> 4, c4 = tid & 15;
#pragma unroll
  for (int i = 0; i < 4; ++i) {
    float4 v = *(const float4*)(src + (size_t)(k0 + r + i * 16) * N + n0 + c4 * 4);
    t[r + i * 16][c4 * 4 + 0] = v.x; t[r + i * 16][c4 * 4 + 1] = v.y;
    t[r + i * 16][c4 * 4 + 2] = v.z; t[r + i * 16][c4 * 4 + 3] = v.w;
  }
  __syncthreads();
#pragma unroll
  for (int i = 0; i < 4; ++i) {
    int idx = tid + i * 256;
    int rn = idx >> 4, ck = idx & 15;
    bf16x4 o = {(bf16_t)t[ck * 4 + 0][rn], (bf16_t)t[ck * 4 + 1][rn],
                (bf16_t)t[ck * 4 + 2][rn], (bf16_t)t[ck * 4 + 3][rn]};
    *(bf16x4*)(dst + (size_t)(n0 + rn) * Kd + k0 + ck * 4) = o;
  }
}

__global__ __launch_bounds__(256) void wtrans_all(const float* __restrict__ wq,
                                                  const float* __restrict__ wk,
                                                  const float* __restrict__ wv,
                                                  const float* __restrict__ wo,
                                                  bf16_t* __restrict__ dqkv,
                                                  bf16_t* __restrict__ dwo) {
  const int by = blockIdx.y, k0 = blockIdx.x * 64;
  if (by < 32)      wtrans_body(wq, dqkv,                        2048, 2048, k0, by * 64);
  else if (by < 40) wtrans_body(wk, dqkv + (size_t)2048 * 2048,  512,  2048, k0, (by - 32) * 64);
  else if (by < 48) wtrans_body(wv, dqkv + (size_t)2560 * 2048,  512,  2048, k0, (by - 40) * 64);
  else              wtrans_body(wo, dwo,                         2048, 2048, k0, (by - 48) * 64);
}

// ---------------------------------------------------------------------------
// bf16 MFMA GEMM: C[M,N] = Ab[M,K] (row-major) @ Wt[N,K]^T
// 128x128 tile, BK=64, 4 waves, 64x64/wave; col-tile pairing keeps RoPE
// partners (d, d+64) in-wave for MODE 1. global_load_lds(16B) staging with
// XOR chunk swizzle. MODE 0: f32 C. MODE 1: QKV epilogue (RoPE via tables).
// ---------------------------------------------------------------------------
template<int MODE>
__global__ __launch_bounds__(256) void gemm_bf16(
    const bf16_t* __restrict__ Ab, const bf16_t* __restrict__ Wt,
    float* __restrict__ Cout, bf16_t* __restrict__ qbuf,
    bf16_t* __restrict__ Kbuf, float* __restrict__ kvout,
    const float* __restrict__ costab, const float* __restrict__ sintab,
    int M, int N, int K) {
  __shared__ bf16_t As[128 * 64];
  __shared__ bf16_t Bs[128 * 64];
  const int tid = threadIdx.x;
  const int w = tid >> 6, lane = tid & 63;
  const int lm = lane & 15, lg = lane >> 4;
  const int wy = w & 1, wx = w >> 1;
  const int mblk = blockIdx.x * 128, nblk = blockIdx.y * 128;

  const int srow = lane >> 3;                 // row within 8-row group
  const int schunk = (lane & 7) ^ srow;       // fetch swizzled chunk
  const bf16_t* Ag = Ab + (size_t)(mblk + w * 32 + srow) * K + schunk * 8;
  const bf16_t* Bg = Wt + (size_t)(nblk + w * 32 + srow) * K + schunk * 8;
  bf16_t* AsW = As + (w * 32) * 64;
  bf16_t* BsW = Bs + (w * 32) * 64;

  f32x4 acc[4][4];
#pragma unroll
  for (int i = 0; i < 4; ++i)
#pragma unroll
    for (int j = 0; j < 4; ++j) acc[i][j] = (f32x4)0.0f;

  const int tcol0 = wx * 2;

  for (int k0 = 0; k0 < K; k0 += 64) {
    __syncthreads();
#pragma unroll
    for (int inst = 0; inst < 4; ++inst) {
      gload_lds16(Ag + (size_t)(inst * 8) * K + k0, AsW + inst * 8 * 64);
      gload_lds16(Bg + (size_t)(inst * 8) * K + k0, BsW + inst * 8 * 64);
    }
    asm volatile("s_waitcnt vmcnt(0)" ::: "memory");
    __syncthreads();
#pragma unroll
    for (int ks = 0; ks < 2; ++ks) {
      const int chunk = ((ks * 4 + lg) ^ (lane & 7)) * 8;
      bf16x8 af[4], bfr[4];
#pragma unroll
      for (int i = 0; i < 4; ++i) {
        int mrow = wy * 64 + i * 16 + lm;
        af[i] = *(const bf16x8*)&As[mrow * 64 + chunk];
      }
#pragma unroll
      for (int j = 0; j < 4; ++j) {
        int tc = tcol0 + (j & 1) + (j >> 1) * 4;
        int nrow = tc * 16 + lm;
        bfr[j] = *(const bf16x8*)&Bs[nrow * 64 + chunk];
      }
#pragma unroll
      for (int i = 0; i < 4; ++i)
#pragma unroll
        for (int j = 0; j < 4; ++j) acc[i][j] = mfma16(af[i], bfr[j], acc[i][j]);
    }
  }

  if (MODE == 0) {
#pragma unroll
    for (int i = 0; i < 4; ++i)
#pragma unroll
      for (int j = 0; j < 4; ++j) {
        int tc = tcol0 + (j & 1) + (j >> 1) * 4;
        int col = nblk + tc * 16 + lm;
#pragma unroll
        for (int r = 0; r < 4; ++r) {
          int row = mblk + wy * 64 + i * 16 + lg * 4 + r;
          Cout[(size_t)row * N + col] = acc[i][j][r];
        }
      }
  } else {
    // QKV epilogue with fused RoPE via tables. d in [0,64), partner d+64.
    const float qscale = 0.08838834764831843f;   // 1/sqrt(128)
#pragma unroll
    for (int i = 0; i < 4; ++i) {
#pragma unroll
      for (int r = 0; r < 4; ++r) {
        int row = mblk + wy * 64 + i * 16 + lg * 4 + r;   // bt
        int ti = row & (TLEN - 1), b = row >> 11;
#pragma unroll
        for (int jp = 0; jp < 2; ++jp) {
          float lo = acc[i][jp][r], hi = acc[i][jp + 2][r];
          int d = wx * 32 + jp * 16 + lm;                 // [0,64)
          int nl = nblk + d;                              // low-half global col
          if (nblk < 2048) {                              // q
            int qh = nl >> 7;
            float cs = costab[ti * 64 + d], sn = sintab[ti * 64 + d];
            float o0 = (lo * cs - hi * sn) * qscale;
            float o1 = (hi * cs + lo * sn) * qscale;
            size_t qo = (((size_t)(b * 16 + qh)) * TLEN + ti) * 128 + d;
            qbuf[qo] = (bf16_t)o0; qbuf[qo + 64] = (bf16_t)o1;
          } else if (nblk < 2560) {                       // k
            int hh = (nl - 2048) >> 7;
            float cs = costab[ti * 64 + d], sn = sintab[ti * 64 + d];
            float o0 = lo * cs - hi * sn;
            float o1 = hi * cs + lo * sn;
            size_t ko = (((size_t)(b * 4 + hh)) * TLEN + ti) * 128 + d;
            Kbuf[ko] = (bf16_t)o0; Kbuf[ko + 64] = (bf16_t)o1;
            size_t kvo = (size_t)row * 1024 + hh * 256 + d;
            kvout[kvo] = o0; kvout[kvo + 64] = o1;
          } else {                                        // v
            int hh = (nl - 2560) >> 7;
            size_t kvo = (size_t)row * 1024 + hh * 256 + 128 + d;
            kvout[kvo] = lo; kvout[kvo + 64] = hi;
          }
        }
      }
    }
  }
}

// ---------------------------------------------------------------------------
// V transpose: kv f32 [b][ti][h][128v @ +128] -> Vtb bf16 [b][h][d=128][tj=2048]
// ---------------------------------------------------------------------------
__global__ __launch_bounds__(256) void vtrans(const float* __restrict__ kvout,
                                              bf16_t* __restrict__ Vtb) {
  __shared__ bf16_t t[128][72];
  const int bx = blockIdx.x;          // (b*4+h)*32 + tt
  const int tt = bx & 31, bh = bx >> 5;
  const int b = bh >> 2, h = bh & 3;
  const int ti0 = tt * 64;
  const float* src = kvout + ((size_t)b * TLEN + ti0) * 1024 + h * 256 + 128;
  for (int idx = threadIdx.x; idx < 64 * 32; idx += 256) {
    int ti = idx >> 5, c4 = idx & 31;
    float4 v = *(const float4*)(src + (size_t)ti * 1024 + c4 * 4);
    t[c4 * 4 + 0][ti] = (bf16_t)v.x; t[c4 * 4 + 1][ti] = (bf16_t)v.y;
    t[c4 * 4 + 2][ti] = (bf16_t)v.z; t[c4 * 4 + 3][ti] = (bf16_t)v.w;
  }
  __syncthreads();
  bf16_t* dst = Vtb + (size_t)bh * 128 * TLEN + ti0;
  for (int idx = threadIdx.x; idx < 128 * 16; idx += 256) {
    int d = idx >> 4, ck = idx & 15;
    bf16x4 o = {t[d][ck * 4 + 0], t[d][ck * 4 + 1], t[d][ck * 4 + 2], t[d][ck * 4 + 3]};
    *(bf16x4*)(dst + (size_t)d * TLEN + ck * 4) = o;
  }
}

// ---------------------------------------------------------------------------
// Flash attention, bf16 MFMA, LDS-staged K/V shared by all 4 waves.
// Block = (b, qh, 64-row q-tile); wave w owns rows [qt*64+w*16, +16).
// Per 64-col K-tile: cooperative global_load_lds of K (64x128) and V^T
// (128x64) with XOR chunk swizzle; threefry dropout keepmask computed while
// the DMA is in flight (hides L2 latency); two barriers per tile (GEMM
// pattern). P C->A relayout via wave-private LDS strip. Online softmax via
// 16-lane shfl_xor. qt <-> 31-qt pairing across bx +- 512 balances load.
// ---------------------------------------------------------------------------
#define PSTR 68
__global__ __launch_bounds__(256, 3) void attn_flash(
    const bf16_t* __restrict__ qb, const bf16_t* __restrict__ Kb,
    const bf16_t* __restrict__ Vtb, bf16_t* __restrict__ midb) {
  __shared__ bf16_t Ks[64 * 128];    // [tj][d], 16B chunks XOR-swizzled by tj&15
  __shared__ bf16_t Vs[128 * 64];    // [d][tj], 16B chunks XOR-swizzled by d&7
  __shared__ bf16_t P_lds[64 * PSTR];
  const int tid = threadIdx.x;
  const int w = tid >> 6, lane = tid & 63;
  const int lm = lane & 15, lg = lane >> 4;

  const int bx = blockIdx.x;
  const int bhalf = bx >> 9, idx = bx & 511;
  const int bqh = idx & 31, t4 = idx >> 5;          // t4 in 0..15
  const int qt = bhalf ? (31 - t4) : t4;            // 0..31
  const int qh = bqh & 15, b = bqh >> 4;
  const int h = qh & 3, g = qh >> 2;

  const bf16_t* qbase = qb + (((size_t)(b * 16 + qh)) * TLEN + qt * 64 + w * 16) * 128;
  const bf16_t* kbase = Kb + ((size_t)(b * 4 + h)) * TLEN * 128;
  const bf16_t* vbase = Vtb + ((size_t)(b * 4 + h)) * 128 * TLEN;

  // staging geometry (wave w stages K rows w*16..+15, V rows w*32..+31)
  const int krow_l = lane >> 4;              // 0..3 (4 rows per instr)
  const int kchunk = lane & 15;              // 16 chunks of 16B per 256B row
  const int vrow_l = lane >> 3;              // 0..7 (8 rows per instr)
  const int vchunk = (lane & 7) ^ (vrow_l & 7);
  const bf16_t* ksrc[4]; const bf16_t* vsrc[4];
  bf16_t* kdst[4]; bf16_t* vdst[4];
#pragma unroll
  for (int j = 0; j < 4; ++j) {
    int klr = w * 16 + j * 4 + krow_l;       // tile-local K row
    ksrc[j] = kbase + (size_t)klr * 128 + (size_t)((kchunk ^ (j * 4 + krow_l)) * 8);
    kdst[j] = Ks + (w * 16 + j * 4) * 128;
    int vd = w * 32 + j * 8 + vrow_l;        // V row (d)
    vsrc[j] = vbase + (size_t)vd * TLEN + (size_t)(vchunk * 8);
    vdst[j] = Vs + (w * 32 + j * 8) * 64;
  }

  // Q A-frags (16 rows); q already scaled by 1/sqrt(128)
  bf16x8 qf[4];
#pragma unroll
  for (int kk = 0; kk < 4; ++kk)
    qf[kk] = *(const bf16x8*)(qbase + (size_t)lm * 128 + kk * 32 + lg * 8);

  float mrow[4], lrow[4];
  f32x4 Oacc[8];
#pragma unroll
  for (int r = 0; r < 4; ++r) { mrow[r] = -3.0e38f; lrow[r] = 0.f; }
#pragma unroll
  for (int c = 0; c < 8; ++c) Oacc[c] = (f32x4)0.0f;

  const int row0 = qt * 64 + w * 16;           // wave's first q row
  const int nkt = qt + 1;                      // K-tiles (uniform across waves)
  const float L2E = 1.4426950408889634f;
  const uint32_t hdr = (uint32_t)((b * 4 + g) * 4 + h);
  bf16_t* Pw = P_lds + (w * 16) * PSTR;

  for (int kt = 0; kt < nkt; ++kt) {
    const int tj0 = kt * 64;
    __syncthreads();                           // prev iter's LDS reads done
    // ---- async stage K,V tiles (8 DMA instrs per wave) ----
#pragma unroll
    for (int j = 0; j < 4; ++j) gload_lds16(ksrc[j] + (size_t)tj0 * 128, kdst[j]);
#pragma unroll
    for (int j = 0; j < 4; ++j) gload_lds16(vsrc[j] + tj0, vdst[j]);

    // ---- threefry keepmask for this tile (overlaps DMA latency) ----
    uint32_t km = 0;
#pragma unroll
    for (int r = 0; r < 4; ++r) {
      uint32_t cb = (hdr << 22) + ((uint32_t)(row0 + lg * 4 + r) << 11)
                  + (uint32_t)(tj0 + lm);
#pragma unroll
      for (int ct = 0; ct < 4; ++ct) {
        uint32_t bits = threefry_bits(cb + (uint32_t)(ct * 16));
        km |= (bits < 0xE6666600u ? 1u : 0u) << (ct * 4 + r);
      }
    }
    asm volatile("s_waitcnt vmcnt(0)" ::: "memory");
    __syncthreads();                           // K/V tile visible to all waves

    // ---- S = Q K^T (K frags from LDS) ----
    f32x4 S[4];
#pragma unroll
    for (int ct = 0; ct < 4; ++ct) {
      S[ct] = (f32x4)0.0f;
      bf16x8 kf[4];
#pragma unroll
      for (int kk = 0; kk < 4; ++kk)
        kf[kk] = *(const bf16x8*)&Ks[(ct * 16 + lm) * 128 + ((kk * 4 + lg) ^ lm) * 8];
#pragma unroll
      for (int kk = 0; kk < 4; ++kk) S[ct] = mfma16(qf[kk], kf[kk], S[ct]);
    }

    // ---- causal mask (diagonal tile only) ----
    if (tj0 + 63 > row0) {
#pragma unroll
      for (int ct = 0; ct < 4; ++ct) {
        int tj = tj0 + ct * 16 + lm;
#pragma unroll
        for (int r = 0; r < 4; ++r) {
          int ti = row0 + lg * 4 + r;
          if (tj > ti) S[ct][r] = -1.0e30f;
        }
      }
    }

    // ---- online softmax ----
    float alpha[4];
    {
      float pm[4];
#pragma unroll
      for (int r = 0; r < 4; ++r)
        pm[r] = fmaxf(fmaxf(S[0][r], S[1][r]), fmaxf(S[2][r], S[3][r]));
#pragma unroll
      for (int off = 1; off < 16; off <<= 1)
#pragma unroll
        for (int r = 0; r < 4; ++r) pm[r] = fmaxf(pm[r], __shfl_xor(pm[r], off));
#pragma unroll
      for (int r = 0; r < 4; ++r) {
        float mn = fmaxf(mrow[r], pm[r]);
        alpha[r] = exp2f((mrow[r] - mn) * L2E);
        mrow[r] = mn;
      }
      float rs[4] = {0.f, 0.f, 0.f, 0.f};
#pragma unroll
      for (int ct = 0; ct < 4; ++ct)
#pragma unroll
        for (int r = 0; r < 4; ++r) {
          float p = exp2f((S[ct][r] - mrow[r]) * L2E);
          S[ct][r] = p;
          rs[r] += p;
        }
#pragma unroll
      for (int off = 1; off < 16; off <<= 1)
#pragma unroll
        for (int r = 0; r < 4; ++r) rs[r] += __shfl_xor(rs[r], off);
#pragma unroll
      for (int r = 0; r < 4; ++r) lrow[r] = lrow[r] * alpha[r] + rs[r];
    }

    // ---- dropout (keepmask) + bf16 + wave-private LDS (C->A relayout) ----
#pragma unroll
    for (int r = 0; r < 4; ++r) {
      int prow = (lg * 4 + r) * PSTR + lm;
      Pw[prow +  0] = (bf16_t)(((km >> (0 + r)) & 1u)  ? S[0][r] : 0.f);
      Pw[prow + 16] = (bf16_t)(((km >> (4 + r)) & 1u)  ? S[1][r] : 0.f);
      Pw[prow + 32] = (bf16_t)(((km >> (8 + r)) & 1u)  ? S[2][r] : 0.f);
      Pw[prow + 48] = (bf16_t)(((km >> (12 + r)) & 1u) ? S[3][r] : 0.f);
    }
    asm volatile("s_waitcnt lgkmcnt(0)" ::: "memory");

    // ---- O = O*alpha + P V (V frags from LDS) ----
#pragma unroll
    for (int c = 0; c < 8; ++c)
#pragma unroll
      for (int r = 0; r < 4; ++r) Oacc[c][r] *= alpha[r];

    bf16x8 aP[2];
#pragma unroll
    for (int kk = 0; kk < 2; ++kk)
      aP[kk] = *(const bf16x8*)&Pw[lm * PSTR + kk * 32 + lg * 8];
#pragma unroll
    for (int c = 0; c < 8; ++c) {
      bf16x8 vf[2];
#pragma unroll
      for (int kk = 0; kk < 2; ++kk)
        vf[kk] = *(const bf16x8*)&Vs[(c * 16 + lm) * 64 + ((kk * 4 + lg) ^ (lm & 7)) * 8];
#pragma unroll
      for (int kk = 0; kk < 2; ++kk) Oacc[c] = mfma16(aP[kk], vf[kk], Oacc[c]);
    }
  }

  // ---- epilogue: normalize (1/l) * (1/0.9), write bf16 mid ----
  float invl[4];
#pragma unroll
  for (int r = 0; r < 4; ++r) invl[r] = (1.0f / 0.9f) / lrow[r];
#pragma unroll
  for (int c = 0; c < 8; ++c) {
    int d = c * 16 + lm;
#pragma unroll
    for (int r = 0; r < 4; ++r) {
      int bt = b * TLEN + row0 + lg * 4 + r;
      midb[(size_t)bt * DEMB + qh * 128 + d] = (bf16_t)(Oacc[c][r] * invl[r]);
    }
  }
}

// ---------------------------------------------------------------------------
extern "C" void kernel_launch(void* const* d_in, const int* in_sizes, int n_in,
                              void* d_out, int out_size, void* d_ws, size_t ws_size,
                              hipStream_t stream) {
  const float* x  = (const float*)d_in[0];
  const float* wq = (const float*)d_in[1];
  const float* wk = (const float*)d_in[2];
  const float* wv = (const float*)d_in[3];
  const float* wo = (const float*)d_in[4];
  float* out = (float*)d_out;
  float* kvc = out + ATTN_OUT_ELEMS;                    // [B,T,4,256] f32

  // workspace carve-up (~80.8 MB)
  char* ws = (char*)d_ws;
  bf16_t* Xb     = (bf16_t*)ws;                          ws += (size_t)4096 * 2048 * 2;  // 16.8MB
  bf16_t* Wqkvt  = (bf16_t*)ws;                          ws += (size_t)3072 * 2048 * 2;  // 12.6MB
  bf16_t* Wot    = (bf16_t*)ws;                          ws += (size_t)2048 * 2048 * 2;  // 8.4MB
  bf16_t* qbuf   = (bf16_t*)ws;                          ws += (size_t)2 * 16 * 2048 * 128 * 2; // 16.8MB
  bf16_t* Kbuf   = (bf16_t*)ws;                          ws += (size_t)2 * 4 * 2048 * 128 * 2;  // 4.2MB
  bf16_t* Vtb    = (bf16_t*)ws;                          ws += (size_t)2 * 4 * 128 * 2048 * 2;  // 4.2MB
  bf16_t* midb   = (bf16_t*)ws;                          ws += (size_t)4096 * 2048 * 2;  // 16.8MB
  float*  costab = (float*)ws;                           ws += (size_t)2048 * 64 * 4;    // 0.5MB
  float*  sintab = (float*)ws;                           // 0.5MB

  dim3 blk(256);
  rope_tab<<<512, blk, 0, stream>>>(costab, sintab);
  cvt_bf16<<<8192, blk, 0, stream>>>(x, Xb, 8388608 / 4);
  wtrans_all<<<dim3(32, 80), blk, 0, stream>>>(wq, wk, wv, wo, Wqkvt, Wot);

  gemm_bf16<1><<<dim3(32, 24), blk, 0, stream>>>(Xb, Wqkvt, nullptr, qbuf, Kbuf, kvc,
                                                 costab, sintab, 4096, 3072, 2048);
  vtrans<<<dim3(256), blk, 0, stream>>>(kvc, Vtb);
  attn_flash<<<dim3(1024), blk, 0, stream>>>(qbuf, Kbuf, Vtb, midb);
  gemm_bf16<0><<<dim3(32, 16), blk, 0, stream>>>(midb, Wot, out, nullptr, nullptr, nullptr,
                                                 nullptr, nullptr, 4096, 2048, 2048);
}